// Round 7
// baseline (258.071 us; speedup 1.0000x reference)
//
#include <hip/hip_runtime.h>
#include <stdint.h>

// ---------------------------------------------------------------------------
// MHA forward, MI355X/gfx950. B=2 S=2048 D=1024 H=16 hd=64.
// cvt x -> bf16 | transpose W's | QKV MFMA GEMM -> Q/K [bh][s][64] + V^T |
// flash attn (swapped QK^T, P redistributed via bpermute -> b128 V reads) |
// out GEMM (128x64 tile, 2 blocks/CU, dbuf LDS).
// ---------------------------------------------------------------------------

#define LOG2E 1.44269504088896340736f

typedef __attribute__((ext_vector_type(4))) float f32x4;
typedef __attribute__((ext_vector_type(8))) short short8v;
typedef __attribute__((ext_vector_type(8))) __bf16 bf16x8;
typedef __attribute__((ext_vector_type(2))) __bf16 bf16x2;
typedef __attribute__((ext_vector_type(4))) unsigned uint4v;

__device__ __forceinline__ unsigned short f2bf(float f) {
  unsigned u = __builtin_bit_cast(unsigned, f);
  u += 0x7FFFu + ((u >> 16) & 1u);  // RNE
  return (unsigned short)(u >> 16);
}

__device__ __forceinline__ unsigned pack2(float lo, float hi) {
  return (unsigned)f2bf(lo) | ((unsigned)f2bf(hi) << 16);
}

// pack 2 f32 -> 2 bf16 in one u32 (v_cvt_pk_bf16_f32)
__device__ __forceinline__ unsigned packbf(float lo, float hi) {
  bf16x2 t;
  t[0] = (__bf16)lo;
  t[1] = (__bf16)hi;
  return __builtin_bit_cast(unsigned, t);
}

__device__ __forceinline__ f32x4 mfma16(short8v a, short8v b, f32x4 c) {
  return __builtin_amdgcn_mfma_f32_16x16x32_bf16(
      __builtin_bit_cast(bf16x8, a), __builtin_bit_cast(bf16x8, b), c, 0, 0, 0);
}

// async global->LDS, 16 bytes per lane. LDS dest = wave-uniform base + lane*16.
__device__ __forceinline__ void gload_lds16(const void* g, void* l) {
  __builtin_amdgcn_global_load_lds(
      (const __attribute__((address_space(1))) void*)(uintptr_t)g,
      (__attribute__((address_space(3))) void*)(uintptr_t)l, 16, 0, 0);
}

// ---------------------------------------------------------------------------
__global__ void cvt_x_kernel(const float4* __restrict__ src,
                             uint2* __restrict__ dst, int n4) {
  int i = blockIdx.x * 256 + threadIdx.x;
  if (i < n4) {
    float4 v = src[i];
    dst[i] = make_uint2(pack2(v.x, v.y), pack2(v.z, v.w));
  }
}

// f32 [R][C] -> bf16 [C][R]
__global__ void transpose_cvt_kernel(const float* __restrict__ src,
                                     unsigned short* __restrict__ dst,
                                     int R, int C) {
  __shared__ unsigned short tile[64][65];
  int tc = threadIdx.x & 63;
  int tr = threadIdx.x >> 6;
  int c0 = blockIdx.x * 64;
  int r0 = blockIdx.y * 64;
#pragma unroll
  for (int i = 0; i < 16; ++i) {
    int r = tr * 16 + i;
    tile[r][tc] = f2bf(src[(size_t)(r0 + r) * C + c0 + tc]);
  }
  __syncthreads();
#pragma unroll
  for (int i = 0; i < 16; ++i) {
    int cc = tr * 16 + i;
    dst[(size_t)(c0 + cc) * R + r0 + tc] = tile[tc][cc];
  }
}

// ---------------------------------------------------------------------------
// QKV GEMM: [4096,1024]bf16 @ WT[3072,1024]bf16 + bias -> Q/K [bh][2048][64],
// V^T [bh][64][2048], all bf16. 128x128 tile, BK=64, 4 waves (2x2 of 64x64).
// Single-buffered: 3 blocks/CU provide the implicit overlap (m97 pattern).
__global__ __launch_bounds__(256, 2)
void gemm_qkv_kernel(const unsigned short* __restrict__ xbf,
                     const unsigned short* __restrict__ WT,
                     const float* __restrict__ bias,
                     unsigned short* __restrict__ Qb,
                     unsigned short* __restrict__ Kb,
                     unsigned short* __restrict__ VbT) {
  const int K = 1024;
  __shared__ __align__(16) unsigned short As[128 * 64];
  __shared__ __align__(16) unsigned short Bs[128 * 64];
  int tid = threadIdx.x;
  int lane = tid & 63;
  int wid = tid >> 6;
  int m0 = blockIdx.y * 128;
  int n0 = blockIdx.x * 128;
  int wm = (wid >> 1) * 64;
  int wn = (wid & 1) * 64;
  f32x4 acc[4][4] = {};
  for (int k0 = 0; k0 < K; k0 += 64) {
#pragma unroll
    for (int it = 0; it < 4; ++it) {
      int G = it * 256 + tid;
      int r = G >> 3, g = G & 7;
      int sg = g ^ (r & 7);  // inverse-swizzled source, linear LDS dest
      gload_lds16(xbf + (size_t)(m0 + r) * K + k0 + sg * 8, &As[G * 8]);
      gload_lds16(WT + (size_t)(n0 + r) * K + k0 + sg * 8, &Bs[G * 8]);
    }
    __syncthreads();
#pragma unroll
    for (int ks = 0; ks < 2; ++ks) {
      short8v a[4], bf[4];
      int kg = ks * 4 + (lane >> 4);
#pragma unroll
      for (int i = 0; i < 4; ++i) {
        int ra = wm + i * 16 + (lane & 15);
        a[i] = *(const short8v*)&As[ra * 64 + ((kg ^ (ra & 7)) << 3)];
        int rb = wn + i * 16 + (lane & 15);
        bf[i] = *(const short8v*)&Bs[rb * 64 + ((kg ^ (rb & 7)) << 3)];
      }
#pragma unroll
      for (int i = 0; i < 4; ++i)
#pragma unroll
        for (int j = 0; j < 4; ++j)
          acc[i][j] = mfma16(a[i], bf[j], acc[i][j]);
    }
    __syncthreads();
  }
  // epilogue: n -> (h, t, d); t=0 Q, t=1 K, t=2 V(transposed)
#pragma unroll
  for (int i = 0; i < 4; ++i) {
#pragma unroll
    for (int j = 0; j < 4; ++j) {
      int n = n0 + wn + j * 16 + (lane & 15);
      float bv = bias[n];
      int h = n / 192;
      int rr = n - h * 192;
      int t = rr >> 6;
      int d = rr & 63;
#pragma unroll
      for (int rg = 0; rg < 4; ++rg) {
        int m = m0 + wm + i * 16 + ((lane >> 4) << 2) + rg;
        int b = m >> 11, s = m & 2047;
        unsigned short val = f2bf(acc[i][j][rg] + bv);
        int bh = b * 16 + h;
        if (t == 2) {
          VbT[((size_t)bh * 64 + d) * 2048 + s] = val;
        } else {
          unsigned short* dst = (t == 0) ? Qb : Kb;
          dst[((size_t)bh * 2048 + s) * 64 + d] = val;
        }
      }
    }
  }
}

// ---------------------------------------------------------------------------
// Flash attention, swapped QK^T. Block = (b,h,qtile of 64). 4 waves x 16 q.
// Lane (hi,q=lq) holds S^T[k][q]; softmax lane-local. P redistributed to
// natural kv order via bpermute so V reads are b128 (conflict-free, K-pattern).

#define ATTN_STAGE(kt_, bi_)                                                  \
  do {                                                                        \
    _Pragma("unroll") for (int it_ = 0; it_ < 2; ++it_) {                     \
      int G_ = it_ * 256 + tid;                                               \
      int r_ = G_ >> 3, g_ = G_ & 7;                                          \
      int sg_ = g_ ^ (r_ & 7);                                                \
      gload_lds16(Kb + bh_off + (size_t)((kt_)*64 + r_) * 64 + sg_ * 8,       \
                  &Ks[bi_][G_ * 8]);                                          \
      gload_lds16(VbT + bh_off + (size_t)r_ * 2048 + (kt_)*64 + sg_ * 8,      \
                  &Vs[bi_][G_ * 8]);                                          \
    }                                                                         \
  } while (0)

#define ATTN_TILE(kt_, CUR_)                                                  \
  do {                                                                        \
    if ((kt_) < 31) ATTN_STAGE((kt_) + 1, (CUR_) ^ 1);                        \
    /* mask: 4x float4; lane covers k = 16f+4hi+{0..3} of row q */            \
    f32x4 mk_[4];                                                             \
    _Pragma("unroll") for (int f = 0; f < 4; ++f)                             \
        mk_[f] = *(const f32x4*)(mrowq + (size_t)(kt_)*64 + f * 16);          \
    /* swapped QK^T: sf[f][r] = S^T[k=16f+4hi+r][q] */                        \
    f32x4 sf[4] = {};                                                         \
    _Pragma("unroll") for (int ks = 0; ks < 2; ++ks) {                        \
      short8v qa = ks ? qa1 : qa0;                                            \
      int kg = ks * 4 + hi;                                                   \
      _Pragma("unroll") for (int f = 0; f < 4; ++f) {                         \
        int row = f * 16 + lq;                                                \
        short8v kb =                                                          \
            *(const short8v*)&Ks[CUR_][row * 64 + ((kg ^ (row & 7)) << 3)];   \
        sf[f] = mfma16(kb, qa, sf[f]);                                        \
      }                                                                       \
    }                                                                         \
    _Pragma("unroll") for (int f = 0; f < 4; ++f)                             \
        _Pragma("unroll") for (int r = 0; r < 4; ++r)                         \
            sf[f][r] = fmaf(sf[f][r], 0.125f, mk_[f][r]);                     \
    /* per-q tile max: local 15-op tree + 2 shfls over hi bits */             \
    float mx0_ = fmaxf(fmaxf(sf[0][0], sf[0][1]), fmaxf(sf[0][2], sf[0][3])); \
    float mx1_ = fmaxf(fmaxf(sf[1][0], sf[1][1]), fmaxf(sf[1][2], sf[1][3])); \
    float mx2_ = fmaxf(fmaxf(sf[2][0], sf[2][1]), fmaxf(sf[2][2], sf[2][3])); \
    float mx3_ = fmaxf(fmaxf(sf[3][0], sf[3][1]), fmaxf(sf[3][2], sf[3][3])); \
    float mt_ = fmaxf(fmaxf(mx0_, mx1_), fmaxf(mx2_, mx3_));                  \
    mt_ = fmaxf(mt_, __shfl_xor(mt_, 16));                                    \
    mt_ = fmaxf(mt_, __shfl_xor(mt_, 32));                                    \
    /* defer-max */                                                           \
    if (!__all(mt_ <= m_s + THR)) {                                           \
      float mn_ = fmaxf(m_s, mt_);                                            \
      float al_ = exp2f((m_s - mn_) * LOG2E);                                 \
      m_s = mn_;                                                              \
      mLs = mn_ * LOG2E;                                                      \
      l_s *= al_;                                                             \
      float a0_ = __shfl(al_, (lane & 48) | hi4);                             \
      float a1_ = __shfl(al_, (lane & 48) | (hi4 + 1));                       \
      float a2_ = __shfl(al_, (lane & 48) | (hi4 + 2));                       \
      float a3_ = __shfl(al_, (lane & 48) | (hi4 + 3));                       \
      _Pragma("unroll") for (int f = 0; f < 4; ++f) {                         \
        o[f][0] *= a0_; o[f][1] *= a1_; o[f][2] *= a2_; o[f][3] *= a3_;       \
      }                                                                       \
    }                                                                         \
    /* P = exp2(sc*log2e - mLs), pack pairs (consecutive k) to bf16 */        \
    unsigned pk_[4][2];                                                       \
    _Pragma("unroll") for (int f = 0; f < 4; ++f) {                           \
      float p0_ = exp2f(fmaf(sf[f][0], LOG2E, -mLs));                         \
      float p1_ = exp2f(fmaf(sf[f][1], LOG2E, -mLs));                         \
      float p2_ = exp2f(fmaf(sf[f][2], LOG2E, -mLs));                         \
      float p3_ = exp2f(fmaf(sf[f][3], LOG2E, -mLs));                         \
      l_s += (p0_ + p1_) + (p2_ + p3_);                                       \
      pk_[f][0] = packbf(p0_, p1_);                                           \
      pk_[f][1] = packbf(p2_, p3_);                                           \
    }                                                                         \
    /* PV: rebuild pa in NATURAL kv order via bpermute; then V reads are   */ \
    /* b128 at slot kg=4ks+hi (identical pattern to K reads: 0 conflicts). */ \
    /* A elem (hi,e) needs kv=32ks+8hi+e = pk_[2ks+(hi>>1)] @ lane         */ \
    /* lq|(2(hi&1)+{0,1})<<4.                                              */ \
    _Pragma("unroll") for (int ks = 0; ks < 2; ++ks) {                        \
      unsigned s0_ = __shfl(pk_[2 * ks][0], sha_);                            \
      unsigned s1_ = __shfl(pk_[2 * ks][1], sha_);                            \
      unsigned s2_ = __shfl(pk_[2 * ks][0], shb_);                            \
      unsigned s3_ = __shfl(pk_[2 * ks][1], shb_);                            \
      unsigned t0_ = __shfl(pk_[2 * ks + 1][0], sha_);                        \
      unsigned t1_ = __shfl(pk_[2 * ks + 1][1], sha_);                        \
      unsigned t2_ = __shfl(pk_[2 * ks + 1][0], shb_);                        \
      unsigned t3_ = __shfl(pk_[2 * ks + 1][1], shb_);                        \
      uint4v au_;                                                             \
      au_[0] = hilo_ ? s0_ : t0_;                                             \
      au_[1] = hilo_ ? s1_ : t1_;                                             \
      au_[2] = hilo_ ? s2_ : t2_;                                             \
      au_[3] = hilo_ ? s3_ : t3_;                                             \
      short8v pa = __builtin_bit_cast(short8v, au_);                          \
      int kg = ks * 4 + hi;                                                   \
      _Pragma("unroll") for (int f = 0; f < 4; ++f) {                         \
        int vrow_ = f * 16 + lq;                                              \
        short8v vb_ =                                                         \
            *(const short8v*)&Vs[CUR_][vrow_ * 64 + ((kg ^ (vrow_ & 7)) << 3)]; \
        o[f] = mfma16(pa, vb_, o[f]);                                         \
      }                                                                       \
    }                                                                         \
    __syncthreads();                                                          \
  } while (0)

__global__ __launch_bounds__(256, 4)
void attn_kernel(const unsigned short* __restrict__ Qb,
                 const unsigned short* __restrict__ Kb,
                 const unsigned short* __restrict__ VbT,
                 const float* __restrict__ mask,
                 unsigned short* __restrict__ vals) {
  __shared__ __align__(16) unsigned short Ks[2][64 * 64];
  __shared__ __align__(16) unsigned short Vs[2][64 * 64];
  int tid = threadIdx.x;
  int lane = tid & 63;
  int wid = tid >> 6;
  int lq = lane & 15;
  int hi = lane >> 4;
  int hi4 = hi << 2;
  int sha_ = lq | ((hi & 1) << 5);   // lane holding kv=32ks+8hi+{0..3}
  int shb_ = sha_ | 16;              // lane holding kv=32ks+8hi+{4..7}
  bool hilo_ = (hi < 2);             // f' = 2ks + (hi>>1) select
  int h = blockIdx.x & 15;           // h innermost: mask tile L2 reuse
  int qt = (blockIdx.x >> 4) & 31;
  int b = blockIdx.x >> 9;
  int bh = b * 16 + h;
  size_t bh_off = (size_t)bh * 2048 * 64;
  int q0 = qt * 64 + wid * 16;

  const unsigned short* qptr =
      Qb + bh_off + (size_t)(q0 + lq) * 64 + (hi << 3);
  short8v qa0 = *(const short8v*)qptr;
  short8v qa1 = *(const short8v*)(qptr + 32);

  f32x4 o[4] = {};
  float m_s = -1e30f, l_s = 0.f, mLs = 0.f;

  const float* mrowq = mask + ((size_t)b * 2048 + q0 + lq) * 2048 + hi4;

  const float THR = 4.0f;

  ATTN_STAGE(0, 0);
  __syncthreads();

  for (int t = 0; t < 16; ++t) {
    ATTN_TILE(2 * t, 0);
    ATTN_TILE(2 * t + 1, 1);
  }

  // deferred row-sum reduction across hi lanes, then broadcast per o-row
  l_s += __shfl_xor(l_s, 16);
  l_s += __shfl_xor(l_s, 32);
  float ri_ = 1.0f / l_s;
  float rv_[4];
#pragma unroll
  for (int r = 0; r < 4; ++r) rv_[r] = __shfl(ri_, (lane & 48) | (hi4 + r));

  // epilogue: scrambled reshape (b,h,s,d) -> (b, h*128 + s/16, (s%16)*64 + d)
#pragma unroll
  for (int f = 0; f < 4; ++f)
#pragma unroll
    for (int r = 0; r < 4; ++r) {
      int s = q0 + hi4 + r;
      int d = f * 16 + lq;
      int s2 = h * 128 + (s >> 4);
      int c2 = ((s & 15) << 6) + d;
      vals[((size_t)b * 2048 + s2) * 1024 + c2] = f2bf(o[f][r] * rv_[r]);
    }
}

// ---------------------------------------------------------------------------
// Output GEMM: vals[4096,1024]bf16 @ WoT[1024,1024]bf16 + bo -> out f32.
// BM=128 BN=64 -> grid 512 (2 blocks/CU) + explicit LDS dbuf (stage next
// before compute, one barrier/step): gemm_out was 1 block/CU with exposed
// stage latency. 4 waves as 2x2 of 64m x 32n.

#define OUT_STAGE(k0_, bi_)                                                   \
  do {                                                                        \
    _Pragma("unroll") for (int it_ = 0; it_ < 4; ++it_) {                     \
      int G_ = it_ * 256 + tid;                                               \
      int r_ = G_ >> 3, g_ = G_ & 7;                                          \
      int sg_ = g_ ^ (r_ & 7);                                                \
      gload_lds16(vals + (size_t)(m0 + r_) * 1024 + (k0_) + sg_ * 8,          \
                  &As[bi_][G_ * 8]);                                          \
    }                                                                         \
    _Pragma("unroll") for (int it_ = 0; it_ < 2; ++it_) {                     \
      int G_ = it_ * 256 + tid;                                               \
      int r_ = G_ >> 3, g_ = G_ & 7;                                          \
      int sg_ = g_ ^ (r_ & 7);                                                \
      gload_lds16(WoT + (size_t)(n0 + r_) * 1024 + (k0_) + sg_ * 8,           \
                  &Bs[bi_][G_ * 8]);                                          \
    }                                                                         \
  } while (0)

#define OUT_STEP(k0_, CUR_)                                                   \
  do {                                                                        \
    if ((k0_) + 64 < 1024) OUT_STAGE((k0_) + 64, (CUR_) ^ 1);                 \
    _Pragma("unroll") for (int ks = 0; ks < 2; ++ks) {                        \
      short8v a_[4], b_[2];                                                   \
      int kg = ks * 4 + hi;                                                   \
      _Pragma("unroll") for (int i = 0; i < 4; ++i) {                         \
        int ra = wm + i * 16 + lq;                                            \
        a_[i] = *(const short8v*)&As[CUR_][ra * 64 + ((kg ^ (ra & 7)) << 3)]; \
      }                                                                       \
      _Pragma("unroll") for (int j = 0; j < 2; ++j) {                         \
        int rb = wn + j * 16 + lq;                                            \
        b_[j] = *(const short8v*)&Bs[CUR_][rb * 64 + ((kg ^ (rb & 7)) << 3)]; \
      }                                                                       \
      _Pragma("unroll") for (int i = 0; i < 4; ++i)                           \
          _Pragma("unroll") for (int j = 0; j < 2; ++j)                       \
              acc[i][j] = mfma16(a_[i], b_[j], acc[i][j]);                    \
    }                                                                         \
    __syncthreads();                                                          \
  } while (0)

__global__ __launch_bounds__(256, 2)
void gemm_out_kernel(const unsigned short* __restrict__ vals,
                     const unsigned short* __restrict__ WoT,
                     const float* __restrict__ bo,
                     float* __restrict__ out) {
  __shared__ __align__(16) unsigned short As[2][128 * 64];
  __shared__ __align__(16) unsigned short Bs[2][64 * 64];
  int tid = threadIdx.x;
  int lane = tid & 63;
  int wid = tid >> 6;
  int lq = lane & 15;
  int hi = lane >> 4;
  int m0 = blockIdx.y * 128;
  int n0 = blockIdx.x * 64;
  int wm = (wid >> 1) * 64;
  int wn = (wid & 1) * 32;
  f32x4 acc[4][2] = {};

  OUT_STAGE(0, 0);
  __syncthreads();
#pragma unroll 1
  for (int kk = 0; kk < 8; ++kk) {
    OUT_STEP(kk * 128, 0);
    OUT_STEP(kk * 128 + 64, 1);
  }

#pragma unroll
  for (int i = 0; i < 4; ++i) {
#pragma unroll
    for (int j = 0; j < 2; ++j) {
      int n = n0 + wn + j * 16 + lq;
      float bv = bo[n];
#pragma unroll
      for (int rg = 0; rg < 4; ++rg) {
        int m = m0 + wm + i * 16 + (hi << 2) + rg;
        out[(size_t)m * 1024 + n] = acc[i][j][rg] + bv;
      }
    }
  }
}

// ---------------------------------------------------------------------------
extern "C" void kernel_launch(void* const* d_in, const int* in_sizes, int n_in,
                              void* d_out, int out_size, void* d_ws,
                              size_t ws_size, hipStream_t stream) {
  const float* x    = (const float*)d_in[0];
  const float* mask = (const float*)d_in[1];
  const float* Wqkv = (const float*)d_in[2];
  const float* bqkv = (const float*)d_in[3];
  const float* Wo   = (const float*)d_in[4];
  const float* bo   = (const float*)d_in[5];
  float* out = (float*)d_out;

  char* ws = (char*)d_ws;
  // layout (bytes): xbf 8M | WqkvT 6M | WoT 2M | Qb 8M | Kb 8M | VbT 8M
  // vals aliases xbf (x dead after gemm_qkv). Total 40 MB.
  unsigned short* xbf   = (unsigned short*)(ws);
  unsigned short* WqkvT = (unsigned short*)(ws + 8388608);
  unsigned short* WoT   = (unsigned short*)(ws + 14680064);
  unsigned short* Qb    = (unsigned short*)(ws + 16777216);
  unsigned short* Kb    = (unsigned short*)(ws + 25165824);
  unsigned short* VbT   = (unsigned short*)(ws + 33554432);
  unsigned short* vals  = xbf;  // reuse

  hipLaunchKernelGGL(cvt_x_kernel, dim3(4096), dim3(256), 0, stream,
                     (const float4*)x, (uint2*)xbf, 1048576);
  hipLaunchKernelGGL(transpose_cvt_kernel, dim3(48, 16), dim3(256), 0, stream,
                     Wqkv, WqkvT, 1024, 3072);
  hipLaunchKernelGGL(transpose_cvt_kernel, dim3(16, 16), dim3(256), 0, stream,
                     Wo, WoT, 1024, 1024);
  hipLaunchKernelGGL(gemm_qkv_kernel, dim3(24, 32), dim3(256), 0, stream,
                     xbf, WqkvT, bqkv, Qb, Kb, VbT);
  hipLaunchKernelGGL(attn_kernel, dim3(1024), dim3(256), 0, stream,
                     Qb, Kb, VbT, mask, vals);
  hipLaunchKernelGGL(gemm_out_kernel, dim3(16, 32), dim3(256), 0, stream,
                     vals, WoT, bo, out);
}

// Round 8
// 244.863 us; speedup vs baseline: 1.0539x; 1.0539x over previous
//
#include <hip/hip_runtime.h>
#include <stdint.h>

// ---------------------------------------------------------------------------
// MHA forward, MI355X/gfx950. B=2 S=2048 D=1024 H=16 hd=64.
// prep (fused cvt+transposes) | QKV MFMA GEMM -> Q/K [bh][s][64] + V^T |
// flash attn (swapped QK^T, reg P->PV via kv-permuted b64 V reads, mask
// register dbuf) | out GEMM (128x64, dbuf).
// ---------------------------------------------------------------------------

#define LOG2E 1.44269504088896340736f

typedef __attribute__((ext_vector_type(4))) float f32x4;
typedef __attribute__((ext_vector_type(8))) short short8v;
typedef __attribute__((ext_vector_type(4))) short short4v;
typedef __attribute__((ext_vector_type(8))) __bf16 bf16x8;
typedef __attribute__((ext_vector_type(2))) __bf16 bf16x2;
typedef __attribute__((ext_vector_type(4))) unsigned uint4v;

__device__ __forceinline__ unsigned short f2bf(float f) {
  unsigned u = __builtin_bit_cast(unsigned, f);
  u += 0x7FFFu + ((u >> 16) & 1u);  // RNE
  return (unsigned short)(u >> 16);
}

__device__ __forceinline__ unsigned pack2(float lo, float hi) {
  return (unsigned)f2bf(lo) | ((unsigned)f2bf(hi) << 16);
}

// pack 2 f32 -> 2 bf16 in one u32 (v_cvt_pk_bf16_f32)
__device__ __forceinline__ unsigned packbf(float lo, float hi) {
  bf16x2 t;
  t[0] = (__bf16)lo;
  t[1] = (__bf16)hi;
  return __builtin_bit_cast(unsigned, t);
}

__device__ __forceinline__ f32x4 mfma16(short8v a, short8v b, f32x4 c) {
  return __builtin_amdgcn_mfma_f32_16x16x32_bf16(
      __builtin_bit_cast(bf16x8, a), __builtin_bit_cast(bf16x8, b), c, 0, 0, 0);
}

// async global->LDS, 16 bytes per lane. LDS dest = wave-uniform base + lane*16.
__device__ __forceinline__ void gload_lds16(const void* g, void* l) {
  __builtin_amdgcn_global_load_lds(
      (const __attribute__((address_space(1))) void*)(uintptr_t)g,
      (__attribute__((address_space(3))) void*)(uintptr_t)l, 16, 0, 0);
}

// ---------------------------------------------------------------------------
// Fused prep: blocks [0,4096) cvt x->bf16; [4096,4864) transpose Wqkv;
// [4864,5120) transpose Wo. One launch instead of three.
__global__ void prep_kernel(const float4* __restrict__ x4,
                            uint2* __restrict__ xd,
                            const float* __restrict__ Wq,
                            unsigned short* __restrict__ WqT,
                            const float* __restrict__ Wo,
                            unsigned short* __restrict__ WoT) {
  __shared__ unsigned short tile[64][65];
  int bb = blockIdx.x;
  if (bb < 4096) {
    int i = bb * 256 + threadIdx.x;
    float4 v = x4[i];
    xd[i] = make_uint2(pack2(v.x, v.y), pack2(v.z, v.w));
    return;
  }
  const float* src;
  unsigned short* dst;
  int C, bx, by;
  if (bb < 4864) {
    int idx = bb - 4096;
    src = Wq; dst = WqT; C = 3072; bx = idx % 48; by = idx / 48;
  } else {
    int idx = bb - 4864;
    src = Wo; dst = WoT; C = 1024; bx = idx & 15; by = idx >> 4;
  }
  int tc = threadIdx.x & 63;
  int tr = threadIdx.x >> 6;
  int c0 = bx * 64, r0 = by * 64;
#pragma unroll
  for (int i = 0; i < 16; ++i) {
    int r = tr * 16 + i;
    tile[r][tc] = f2bf(src[(size_t)(r0 + r) * C + c0 + tc]);
  }
  __syncthreads();
#pragma unroll
  for (int i = 0; i < 16; ++i) {
    int cc = tr * 16 + i;
    dst[(size_t)(c0 + cc) * 1024 + r0 + tc] = tile[tc][cc];
  }
}

// ---------------------------------------------------------------------------
// QKV GEMM: [4096,1024]bf16 @ WT[3072,1024]bf16 + bias -> Q/K [bh][2048][64],
// V^T [bh][64][2048], all bf16. 128x128 tile, BK=64, 4 waves (2x2 of 64x64).
__global__ __launch_bounds__(256, 2)
void gemm_qkv_kernel(const unsigned short* __restrict__ xbf,
                     const unsigned short* __restrict__ WT,
                     const float* __restrict__ bias,
                     unsigned short* __restrict__ Qb,
                     unsigned short* __restrict__ Kb,
                     unsigned short* __restrict__ VbT) {
  const int K = 1024;
  __shared__ __align__(16) unsigned short As[128 * 64];
  __shared__ __align__(16) unsigned short Bs[128 * 64];
  int tid = threadIdx.x;
  int lane = tid & 63;
  int wid = tid >> 6;
  int m0 = blockIdx.y * 128;
  int n0 = blockIdx.x * 128;
  int wm = (wid >> 1) * 64;
  int wn = (wid & 1) * 64;
  f32x4 acc[4][4] = {};
  for (int k0 = 0; k0 < K; k0 += 64) {
#pragma unroll
    for (int it = 0; it < 4; ++it) {
      int G = it * 256 + tid;
      int r = G >> 3, g = G & 7;
      int sg = g ^ (r & 7);  // inverse-swizzled source, linear LDS dest
      gload_lds16(xbf + (size_t)(m0 + r) * K + k0 + sg * 8, &As[G * 8]);
      gload_lds16(WT + (size_t)(n0 + r) * K + k0 + sg * 8, &Bs[G * 8]);
    }
    __syncthreads();
#pragma unroll
    for (int ks = 0; ks < 2; ++ks) {
      short8v a[4], bf[4];
      int kg = ks * 4 + (lane >> 4);
#pragma unroll
      for (int i = 0; i < 4; ++i) {
        int ra = wm + i * 16 + (lane & 15);
        a[i] = *(const short8v*)&As[ra * 64 + ((kg ^ (ra & 7)) << 3)];
        int rb = wn + i * 16 + (lane & 15);
        bf[i] = *(const short8v*)&Bs[rb * 64 + ((kg ^ (rb & 7)) << 3)];
      }
#pragma unroll
      for (int i = 0; i < 4; ++i)
#pragma unroll
        for (int j = 0; j < 4; ++j)
          acc[i][j] = mfma16(a[i], bf[j], acc[i][j]);
    }
    __syncthreads();
  }
  // epilogue: n -> (h, t, d); t=0 Q, t=1 K, t=2 V(transposed)
#pragma unroll
  for (int i = 0; i < 4; ++i) {
#pragma unroll
    for (int j = 0; j < 4; ++j) {
      int n = n0 + wn + j * 16 + (lane & 15);
      float bv = bias[n];
      int h = n / 192;
      int rr = n - h * 192;
      int t = rr >> 6;
      int d = rr & 63;
#pragma unroll
      for (int rg = 0; rg < 4; ++rg) {
        int m = m0 + wm + i * 16 + ((lane >> 4) << 2) + rg;
        int b = m >> 11, s = m & 2047;
        unsigned short val = f2bf(acc[i][j][rg] + bv);
        int bh = b * 16 + h;
        if (t == 2) {
          VbT[((size_t)bh * 64 + d) * 2048 + s] = val;
        } else {
          unsigned short* dst = (t == 0) ? Qb : Kb;
          dst[((size_t)bh * 2048 + s) * 64 + d] = val;
        }
      }
    }
  }
}

// ---------------------------------------------------------------------------
// Flash attention, swapped QK^T. Block = (b,h,qtile of 64). 4 waves x 16 q.
// Lane (hi,q=lq) holds S^T[k][q]; softmax lane-local; P stays in registers
// (kv-permuted 2xb64 V reads, R5-proven). Mask double-buffered in registers.

#define ATTN_STAGE(kt_, bi_)                                                  \
  do {                                                                        \
    _Pragma("unroll") for (int it_ = 0; it_ < 2; ++it_) {                     \
      int G_ = it_ * 256 + tid;                                               \
      int r_ = G_ >> 3, g_ = G_ & 7;                                          \
      int sg_ = g_ ^ (r_ & 7);                                                \
      gload_lds16(Kb + bh_off + (size_t)((kt_)*64 + r_) * 64 + sg_ * 8,       \
                  &Ks[bi_][G_ * 8]);                                          \
      gload_lds16(VbT + bh_off + (size_t)r_ * 2048 + (kt_)*64 + sg_ * 8,      \
                  &Vs[bi_][G_ * 8]);                                          \
    }                                                                         \
  } while (0)

#define ATTN_TILE(kt_, CUR_, MKC_, MKN_)                                      \
  do {                                                                        \
    if ((kt_) < 31) {                                                         \
      ATTN_STAGE((kt_) + 1, (CUR_) ^ 1);                                      \
      _Pragma("unroll") for (int f = 0; f < 4; ++f)                           \
          MKN_[f] =                                                           \
              *(const f32x4*)(mrowq + (size_t)((kt_) + 1) * 64 + f * 16);     \
    }                                                                         \
    /* swapped QK^T: sf[f][r] = S^T[k=16f+4hi+r][q] */                        \
    f32x4 sf[4] = {};                                                         \
    _Pragma("unroll") for (int ks = 0; ks < 2; ++ks) {                        \
      short8v qa = ks ? qa1 : qa0;                                            \
      int kg = ks * 4 + hi;                                                   \
      _Pragma("unroll") for (int f = 0; f < 4; ++f) {                         \
        int row = f * 16 + lq;                                                \
        short8v kb =                                                          \
            *(const short8v*)&Ks[CUR_][row * 64 + ((kg ^ (row & 7)) << 3)];   \
        sf[f] = mfma16(kb, qa, sf[f]);                                        \
      }                                                                       \
    }                                                                         \
    _Pragma("unroll") for (int f = 0; f < 4; ++f)                             \
        _Pragma("unroll") for (int r = 0; r < 4; ++r)                         \
            sf[f][r] = fmaf(sf[f][r], 0.125f, MKC_[f][r]);                    \
    /* per-q tile max: local 15-op tree + 2 shfls over hi bits */             \
    float mx0_ = fmaxf(fmaxf(sf[0][0], sf[0][1]), fmaxf(sf[0][2], sf[0][3])); \
    float mx1_ = fmaxf(fmaxf(sf[1][0], sf[1][1]), fmaxf(sf[1][2], sf[1][3])); \
    float mx2_ = fmaxf(fmaxf(sf[2][0], sf[2][1]), fmaxf(sf[2][2], sf[2][3])); \
    float mx3_ = fmaxf(fmaxf(sf[3][0], sf[3][1]), fmaxf(sf[3][2], sf[3][3])); \
    float mt_ = fmaxf(fmaxf(mx0_, mx1_), fmaxf(mx2_, mx3_));                  \
    mt_ = fmaxf(mt_, __shfl_xor(mt_, 16));                                    \
    mt_ = fmaxf(mt_, __shfl_xor(mt_, 32));                                    \
    /* defer-max */                                                           \
    if (!__all(mt_ <= m_s + THR)) {                                           \
      float mn_ = fmaxf(m_s, mt_);                                            \
      float al_ = exp2f((m_s - mn_) * LOG2E);                                 \
      m_s = mn_;                                                              \
      mLs = mn_ * LOG2E;                                                      \
      l_s *= al_;                                                             \
      float a0_ = __shfl(al_, (lane & 48) | hi4);                             \
      float a1_ = __shfl(al_, (lane & 48) | (hi4 + 1));                       \
      float a2_ = __shfl(al_, (lane & 48) | (hi4 + 2));                       \
      float a3_ = __shfl(al_, (lane & 48) | (hi4 + 3));                       \
      _Pragma("unroll") for (int f = 0; f < 4; ++f) {                         \
        o[f][0] *= a0_; o[f][1] *= a1_; o[f][2] *= a2_; o[f][3] *= a3_;       \
      }                                                                       \
    }                                                                         \
    /* P = exp2(sc*log2e - mLs), pack pairs (consecutive k) to bf16 */        \
    unsigned pk_[4][2];                                                       \
    _Pragma("unroll") for (int f = 0; f < 4; ++f) {                           \
      float p0_ = exp2f(fmaf(sf[f][0], LOG2E, -mLs));                         \
      float p1_ = exp2f(fmaf(sf[f][1], LOG2E, -mLs));                         \
      float p2_ = exp2f(fmaf(sf[f][2], LOG2E, -mLs));                         \
      float p3_ = exp2f(fmaf(sf[f][3], LOG2E, -mLs));                         \
      l_s += (p0_ + p1_) + (p2_ + p3_);                                       \
      pk_[f][0] = packbf(p0_, p1_);                                           \
      pk_[f][1] = packbf(p2_, p3_);                                           \
    }                                                                         \
    /* PV: A-frag = register concat; V read with kv-permutation pi where    */\
    /* slot(8hi+e) -> kv = 32ks + 16*(e>=4) + 4hi + (e&3)  (R5-proven)      */\
    _Pragma("unroll") for (int ks = 0; ks < 2; ++ks) {                        \
      uint4v au_;                                                             \
      au_[0] = pk_[2 * ks][0];                                                \
      au_[1] = pk_[2 * ks][1];                                                \
      au_[2] = pk_[2 * ks + 1][0];                                            \
      au_[3] = pk_[2 * ks + 1][1];                                            \
      short8v pa = __builtin_bit_cast(short8v, au_);                          \
      _Pragma("unroll") for (int f = 0; f < 4; ++f) {                         \
        int vrow_ = f * 16 + lq;                                              \
        int blkA_ = 4 * ks + (hi >> 1);                                       \
        int eA_ = vrow_ * 64 + (((blkA_) ^ (vrow_ & 7)) << 3) +               \
                  ((hi & 1) << 2);                                            \
        int eB_ = vrow_ * 64 + (((blkA_ + 2) ^ (vrow_ & 7)) << 3) +           \
                  ((hi & 1) << 2);                                            \
        short4v vlo_ = *(const short4v*)&Vs[CUR_][eA_];                       \
        short4v vhi_ = *(const short4v*)&Vs[CUR_][eB_];                       \
        short8v vb_;                                                          \
        vb_[0] = vlo_[0]; vb_[1] = vlo_[1]; vb_[2] = vlo_[2];                 \
        vb_[3] = vlo_[3]; vb_[4] = vhi_[0]; vb_[5] = vhi_[1];                 \
        vb_[6] = vhi_[2]; vb_[7] = vhi_[3];                                   \
        o[f] = mfma16(pa, vb_, o[f]);                                         \
      }                                                                       \
    }                                                                         \
    __syncthreads();                                                          \
  } while (0)

__global__ __launch_bounds__(256, 4)
void attn_kernel(const unsigned short* __restrict__ Qb,
                 const unsigned short* __restrict__ Kb,
                 const unsigned short* __restrict__ VbT,
                 const float* __restrict__ mask,
                 unsigned short* __restrict__ vals) {
  __shared__ __align__(16) unsigned short Ks[2][64 * 64];
  __shared__ __align__(16) unsigned short Vs[2][64 * 64];
  int tid = threadIdx.x;
  int lane = tid & 63;
  int wid = tid >> 6;
  int lq = lane & 15;
  int hi = lane >> 4;
  int hi4 = hi << 2;
  int h = blockIdx.x & 15;           // h innermost: mask tile L2 reuse
  int qt = (blockIdx.x >> 4) & 31;
  int b = blockIdx.x >> 9;
  int bh = b * 16 + h;
  size_t bh_off = (size_t)bh * 2048 * 64;
  int q0 = qt * 64 + wid * 16;

  const unsigned short* qptr =
      Qb + bh_off + (size_t)(q0 + lq) * 64 + (hi << 3);
  short8v qa0 = *(const short8v*)qptr;
  short8v qa1 = *(const short8v*)(qptr + 32);

  f32x4 o[4] = {};
  float m_s = -1e30f, l_s = 0.f, mLs = 0.f;

  const float* mrowq = mask + ((size_t)b * 2048 + q0 + lq) * 2048 + hi4;

  const float THR = 4.0f;

  f32x4 mkA[4], mkB[4];
#pragma unroll
  for (int f = 0; f < 4; ++f) mkA[f] = *(const f32x4*)(mrowq + f * 16);
  ATTN_STAGE(0, 0);
  __syncthreads();

  for (int t = 0; t < 16; ++t) {
    ATTN_TILE(2 * t, 0, mkA, mkB);
    ATTN_TILE(2 * t + 1, 1, mkB, mkA);
  }

  // deferred row-sum reduction across hi lanes, then broadcast per o-row
  l_s += __shfl_xor(l_s, 16);
  l_s += __shfl_xor(l_s, 32);
  float ri_ = 1.0f / l_s;
  float rv_[4];
#pragma unroll
  for (int r = 0; r < 4; ++r) rv_[r] = __shfl(ri_, (lane & 48) | (hi4 + r));

  // epilogue: scrambled reshape (b,h,s,d) -> (b, h*128 + s/16, (s%16)*64 + d)
#pragma unroll
  for (int f = 0; f < 4; ++f)
#pragma unroll
    for (int r = 0; r < 4; ++r) {
      int s = q0 + hi4 + r;
      int d = f * 16 + lq;
      int s2 = h * 128 + (s >> 4);
      int c2 = ((s & 15) << 6) + d;
      vals[((size_t)b * 2048 + s2) * 1024 + c2] = f2bf(o[f][r] * rv_[r]);
    }
}

// ---------------------------------------------------------------------------
// Output GEMM: vals[4096,1024]bf16 @ WoT[1024,1024]bf16 + bo -> out f32.
// BM=128 BN=64 -> grid 512 (2 blocks/CU) + LDS dbuf. 4 waves, 64m x 32n each.

#define OUT_STAGE(k0_, bi_)                                                   \
  do {                                                                        \
    _Pragma("unroll") for (int it_ = 0; it_ < 4; ++it_) {                     \
      int G_ = it_ * 256 + tid;                                               \
      int r_ = G_ >> 3, g_ = G_ & 7;                                          \
      int sg_ = g_ ^ (r_ & 7);                                                \
      gload_lds16(vals + (size_t)(m0 + r_) * 1024 + (k0_) + sg_ * 8,          \
                  &As[bi_][G_ * 8]);                                          \
    }                                                                         \
    _Pragma("unroll") for (int it_ = 0; it_ < 2; ++it_) {                     \
      int G_ = it_ * 256 + tid;                                               \
      int r_ = G_ >> 3, g_ = G_ & 7;                                          \
      int sg_ = g_ ^ (r_ & 7);                                                \
      gload_lds16(WoT + (size_t)(n0 + r_) * 1024 + (k0_) + sg_ * 8,           \
                  &Bs[bi_][G_ * 8]);                                          \
    }                                                                         \
  } while (0)

#define OUT_STEP(k0_, CUR_)                                                   \
  do {                                                                        \
    if ((k0_) + 64 < 1024) OUT_STAGE((k0_) + 64, (CUR_) ^ 1);                 \
    _Pragma("unroll") for (int ks = 0; ks < 2; ++ks) {                        \
      short8v a_[4], b_[2];                                                   \
      int kg = ks * 4 + hi;                                                   \
      _Pragma("unroll") for (int i = 0; i < 4; ++i) {                         \
        int ra = wm + i * 16 + lq;                                            \
        a_[i] = *(const short8v*)&As[CUR_][ra * 64 + ((kg ^ (ra & 7)) << 3)]; \
      }                                                                       \
      _Pragma("unroll") for (int j = 0; j < 2; ++j) {                         \
        int rb = wn + j * 16 + lq;                                            \
        b_[j] = *(const short8v*)&Bs[CUR_][rb * 64 + ((kg ^ (rb & 7)) << 3)]; \
      }                                                                       \
      _Pragma("unroll") for (int i = 0; i < 4; ++i)                           \
          _Pragma("unroll") for (int j = 0; j < 2; ++j)                       \
              acc[i][j] = mfma16(a_[i], b_[j], acc[i][j]);                    \
    }                                                                         \
    __syncthreads();                                                          \
  } while (0)

__global__ __launch_bounds__(256, 2)
void gemm_out_kernel(const unsigned short* __restrict__ vals,
                     const unsigned short* __restrict__ WoT,
                     const float* __restrict__ bo,
                     float* __restrict__ out) {
  __shared__ __align__(16) unsigned short As[2][128 * 64];
  __shared__ __align__(16) unsigned short Bs[2][64 * 64];
  int tid = threadIdx.x;
  int lane = tid & 63;
  int wid = tid >> 6;
  int lq = lane & 15;
  int hi = lane >> 4;
  int m0 = blockIdx.y * 128;
  int n0 = blockIdx.x * 64;
  int wm = (wid >> 1) * 64;
  int wn = (wid & 1) * 32;
  f32x4 acc[4][2] = {};

  OUT_STAGE(0, 0);
  __syncthreads();
#pragma unroll 1
  for (int kk = 0; kk < 8; ++kk) {
    OUT_STEP(kk * 128, 0);
    OUT_STEP(kk * 128 + 64, 1);
  }

#pragma unroll
  for (int i = 0; i < 4; ++i) {
#pragma unroll
    for (int j = 0; j < 2; ++j) {
      int n = n0 + wn + j * 16 + lq;
      float bv = bo[n];
#pragma unroll
      for (int rg = 0; rg < 4; ++rg) {
        int m = m0 + wm + i * 16 + (hi << 2) + rg;
        out[(size_t)m * 1024 + n] = acc[i][j][rg] + bv;
      }
    }
  }
}

// ---------------------------------------------------------------------------
extern "C" void kernel_launch(void* const* d_in, const int* in_sizes, int n_in,
                              void* d_out, int out_size, void* d_ws,
                              size_t ws_size, hipStream_t stream) {
  const float* x    = (const float*)d_in[0];
  const float* mask = (const float*)d_in[1];
  const float* Wqkv = (const float*)d_in[2];
  const float* bqkv = (const float*)d_in[3];
  const float* Wo   = (const float*)d_in[4];
  const float* bo   = (const float*)d_in[5];
  float* out = (float*)d_out;

  char* ws = (char*)d_ws;
  // layout (bytes): xbf 8M | WqkvT 6M | WoT 2M | Qb 8M | Kb 8M | VbT 8M
  // vals aliases xbf (x dead after gemm_qkv). Total 40 MB.
  unsigned short* xbf   = (unsigned short*)(ws);
  unsigned short* WqkvT = (unsigned short*)(ws + 8388608);
  unsigned short* WoT   = (unsigned short*)(ws + 14680064);
  unsigned short* Qb    = (unsigned short*)(ws + 16777216);
  unsigned short* Kb    = (unsigned short*)(ws + 25165824);
  unsigned short* VbT   = (unsigned short*)(ws + 33554432);
  unsigned short* vals  = xbf;  // reuse

  hipLaunchKernelGGL(prep_kernel, dim3(5120), dim3(256), 0, stream,
                     (const float4*)x, (uint2*)xbf, Wqkv, WqkvT, Wo, WoT);
  hipLaunchKernelGGL(gemm_qkv_kernel, dim3(24, 32), dim3(256), 0, stream,
                     xbf, WqkvT, bqkv, Qb, Kb, VbT);
  hipLaunchKernelGGL(attn_kernel, dim3(1024), dim3(256), 0, stream,
                     Qb, Kb, VbT, mask, vals);
  hipLaunchKernelGGL(gemm_out_kernel, dim3(16, 32), dim3(256), 0, stream,
                     vals, WoT, bo, out);
}

// Round 9
// 242.615 us; speedup vs baseline: 1.0637x; 1.0093x over previous
//
#include <hip/hip_runtime.h>
#include <stdint.h>

// ---------------------------------------------------------------------------
// MHA forward, MI355X/gfx950. B=2 S=2048 D=1024 H=16 hd=64.
// prep (fused cvt+transposes) | QKV MFMA GEMM (3 blocks/CU, no tail) ->
// Q/K [bh][s][64] + V^T | flash attn (swapped QK^T, reg P->PV, mask reg-dbuf,
// setprio around MFMA) | out GEMM (128x64, dbuf).
// ---------------------------------------------------------------------------

#define LOG2E 1.44269504088896340736f

typedef __attribute__((ext_vector_type(4))) float f32x4;
typedef __attribute__((ext_vector_type(8))) short short8v;
typedef __attribute__((ext_vector_type(4))) short short4v;
typedef __attribute__((ext_vector_type(8))) __bf16 bf16x8;
typedef __attribute__((ext_vector_type(2))) __bf16 bf16x2;
typedef __attribute__((ext_vector_type(4))) unsigned uint4v;

__device__ __forceinline__ unsigned short f2bf(float f) {
  unsigned u = __builtin_bit_cast(unsigned, f);
  u += 0x7FFFu + ((u >> 16) & 1u);  // RNE
  return (unsigned short)(u >> 16);
}

__device__ __forceinline__ unsigned pack2(float lo, float hi) {
  return (unsigned)f2bf(lo) | ((unsigned)f2bf(hi) << 16);
}

// pack 2 f32 -> 2 bf16 in one u32 (v_cvt_pk_bf16_f32)
__device__ __forceinline__ unsigned packbf(float lo, float hi) {
  bf16x2 t;
  t[0] = (__bf16)lo;
  t[1] = (__bf16)hi;
  return __builtin_bit_cast(unsigned, t);
}

__device__ __forceinline__ f32x4 mfma16(short8v a, short8v b, f32x4 c) {
  return __builtin_amdgcn_mfma_f32_16x16x32_bf16(
      __builtin_bit_cast(bf16x8, a), __builtin_bit_cast(bf16x8, b), c, 0, 0, 0);
}

// async global->LDS, 16 bytes per lane. LDS dest = wave-uniform base + lane*16.
__device__ __forceinline__ void gload_lds16(const void* g, void* l) {
  __builtin_amdgcn_global_load_lds(
      (const __attribute__((address_space(1))) void*)(uintptr_t)g,
      (__attribute__((address_space(3))) void*)(uintptr_t)l, 16, 0, 0);
}

// ---------------------------------------------------------------------------
// Fused prep: blocks [0,4096) cvt x->bf16; [4096,4864) transpose Wqkv;
// [4864,5120) transpose Wo.
__global__ void prep_kernel(const float4* __restrict__ x4,
                            uint2* __restrict__ xd,
                            const float* __restrict__ Wq,
                            unsigned short* __restrict__ WqT,
                            const float* __restrict__ Wo,
                            unsigned short* __restrict__ WoT) {
  __shared__ unsigned short tile[64][65];
  int bb = blockIdx.x;
  if (bb < 4096) {
    int i = bb * 256 + threadIdx.x;
    float4 v = x4[i];
    xd[i] = make_uint2(pack2(v.x, v.y), pack2(v.z, v.w));
    return;
  }
  const float* src;
  unsigned short* dst;
  int C, bx, by;
  if (bb < 4864) {
    int idx = bb - 4096;
    src = Wq; dst = WqT; C = 3072; bx = idx % 48; by = idx / 48;
  } else {
    int idx = bb - 4864;
    src = Wo; dst = WoT; C = 1024; bx = idx & 15; by = idx >> 4;
  }
  int tc = threadIdx.x & 63;
  int tr = threadIdx.x >> 6;
  int c0 = bx * 64, r0 = by * 64;
#pragma unroll
  for (int i = 0; i < 16; ++i) {
    int r = tr * 16 + i;
    tile[r][tc] = f2bf(src[(size_t)(r0 + r) * C + c0 + tc]);
  }
  __syncthreads();
#pragma unroll
  for (int i = 0; i < 16; ++i) {
    int cc = tr * 16 + i;
    dst[(size_t)(c0 + cc) * 1024 + r0 + tc] = tile[tc][cc];
  }
}

// ---------------------------------------------------------------------------
// QKV GEMM: [4096,1024]bf16 @ WT[3072,1024]bf16 + bias -> Q/K [bh][2048][64],
// V^T [bh][64][2048], all bf16. 128x128 tile, BK=64, 4 waves (2x2 of 64x64).
// launch_bounds(256,3): grid 768 = 256 CU x 3 -> all blocks co-resident,
// zero dispatch tail, m97-style implicit overlap.
__global__ __launch_bounds__(256, 3)
void gemm_qkv_kernel(const unsigned short* __restrict__ xbf,
                     const unsigned short* __restrict__ WT,
                     const float* __restrict__ bias,
                     unsigned short* __restrict__ Qb,
                     unsigned short* __restrict__ Kb,
                     unsigned short* __restrict__ VbT) {
  const int K = 1024;
  __shared__ __align__(16) unsigned short As[128 * 64];
  __shared__ __align__(16) unsigned short Bs[128 * 64];
  int tid = threadIdx.x;
  int lane = tid & 63;
  int wid = tid >> 6;
  int m0 = blockIdx.y * 128;
  int n0 = blockIdx.x * 128;
  int wm = (wid >> 1) * 64;
  int wn = (wid & 1) * 64;
  f32x4 acc[4][4] = {};
  for (int k0 = 0; k0 < K; k0 += 64) {
#pragma unroll
    for (int it = 0; it < 4; ++it) {
      int G = it * 256 + tid;
      int r = G >> 3, g = G & 7;
      int sg = g ^ (r & 7);  // inverse-swizzled source, linear LDS dest
      gload_lds16(xbf + (size_t)(m0 + r) * K + k0 + sg * 8, &As[G * 8]);
      gload_lds16(WT + (size_t)(n0 + r) * K + k0 + sg * 8, &Bs[G * 8]);
    }
    __syncthreads();
#pragma unroll
    for (int ks = 0; ks < 2; ++ks) {
      short8v a[4], bf[4];
      int kg = ks * 4 + (lane >> 4);
#pragma unroll
      for (int i = 0; i < 4; ++i) {
        int ra = wm + i * 16 + (lane & 15);
        a[i] = *(const short8v*)&As[ra * 64 + ((kg ^ (ra & 7)) << 3)];
        int rb = wn + i * 16 + (lane & 15);
        bf[i] = *(const short8v*)&Bs[rb * 64 + ((kg ^ (rb & 7)) << 3)];
      }
#pragma unroll
      for (int i = 0; i < 4; ++i)
#pragma unroll
        for (int j = 0; j < 4; ++j)
          acc[i][j] = mfma16(a[i], bf[j], acc[i][j]);
    }
    __syncthreads();
  }
  // epilogue: n -> (h, t, d); t=0 Q, t=1 K, t=2 V(transposed)
#pragma unroll
  for (int i = 0; i < 4; ++i) {
#pragma unroll
    for (int j = 0; j < 4; ++j) {
      int n = n0 + wn + j * 16 + (lane & 15);
      float bv = bias[n];
      int h = n / 192;
      int rr = n - h * 192;
      int t = rr >> 6;
      int d = rr & 63;
#pragma unroll
      for (int rg = 0; rg < 4; ++rg) {
        int m = m0 + wm + i * 16 + ((lane >> 4) << 2) + rg;
        int b = m >> 11, s = m & 2047;
        unsigned short val = f2bf(acc[i][j][rg] + bv);
        int bh = b * 16 + h;
        if (t == 2) {
          VbT[((size_t)bh * 64 + d) * 2048 + s] = val;
        } else {
          unsigned short* dst = (t == 0) ? Qb : Kb;
          dst[((size_t)bh * 2048 + s) * 64 + d] = val;
        }
      }
    }
  }
}

// ---------------------------------------------------------------------------
// Flash attention, swapped QK^T. Block = (b,h,qtile of 64). 4 waves x 16 q.
// Lane (hi,q=lq) holds S^T[k][q]; softmax lane-local; P stays in registers
// (kv-permuted 2xb64 V reads). Mask double-buffered in registers. setprio(1)
// around MFMA clusters (T5: independent-block regime, m191 +4-7%).

#define ATTN_STAGE(kt_, bi_)                                                  \
  do {                                                                        \
    _Pragma("unroll") for (int it_ = 0; it_ < 2; ++it_) {                     \
      int G_ = it_ * 256 + tid;                                               \
      int r_ = G_ >> 3, g_ = G_ & 7;                                          \
      int sg_ = g_ ^ (r_ & 7);                                                \
      gload_lds16(Kb + bh_off + (size_t)((kt_)*64 + r_) * 64 + sg_ * 8,       \
                  &Ks[bi_][G_ * 8]);                                          \
      gload_lds16(VbT + bh_off + (size_t)r_ * 2048 + (kt_)*64 + sg_ * 8,      \
                  &Vs[bi_][G_ * 8]);                                          \
    }                                                                         \
  } while (0)

#define ATTN_TILE(kt_, CUR_, MKC_, MKN_)                                      \
  do {                                                                        \
    if ((kt_) < 31) {                                                         \
      ATTN_STAGE((kt_) + 1, (CUR_) ^ 1);                                      \
      _Pragma("unroll") for (int f = 0; f < 4; ++f)                           \
          MKN_[f] =                                                           \
              *(const f32x4*)(mrowq + (size_t)((kt_) + 1) * 64 + f * 16);     \
    }                                                                         \
    /* swapped QK^T: sf[f][r] = S^T[k=16f+4hi+r][q] */                        \
    f32x4 sf[4] = {};                                                         \
    __builtin_amdgcn_s_setprio(1);                                            \
    _Pragma("unroll") for (int ks = 0; ks < 2; ++ks) {                        \
      short8v qa = ks ? qa1 : qa0;                                            \
      int kg = ks * 4 + hi;                                                   \
      _Pragma("unroll") for (int f = 0; f < 4; ++f) {                         \
        int row = f * 16 + lq;                                                \
        short8v kb =                                                          \
            *(const short8v*)&Ks[CUR_][row * 64 + ((kg ^ (row & 7)) << 3)];   \
        sf[f] = mfma16(kb, qa, sf[f]);                                        \
      }                                                                       \
    }                                                                         \
    __builtin_amdgcn_s_setprio(0);                                            \
    _Pragma("unroll") for (int f = 0; f < 4; ++f)                             \
        _Pragma("unroll") for (int r = 0; r < 4; ++r)                         \
            sf[f][r] = fmaf(sf[f][r], 0.125f, MKC_[f][r]);                    \
    /* per-q tile max: local 15-op tree + 2 shfls over hi bits */             \
    float mx0_ = fmaxf(fmaxf(sf[0][0], sf[0][1]), fmaxf(sf[0][2], sf[0][3])); \
    float mx1_ = fmaxf(fmaxf(sf[1][0], sf[1][1]), fmaxf(sf[1][2], sf[1][3])); \
    float mx2_ = fmaxf(fmaxf(sf[2][0], sf[2][1]), fmaxf(sf[2][2], sf[2][3])); \
    float mx3_ = fmaxf(fmaxf(sf[3][0], sf[3][1]), fmaxf(sf[3][2], sf[3][3])); \
    float mt_ = fmaxf(fmaxf(mx0_, mx1_), fmaxf(mx2_, mx3_));                  \
    mt_ = fmaxf(mt_, __shfl_xor(mt_, 16));                                    \
    mt_ = fmaxf(mt_, __shfl_xor(mt_, 32));                                    \
    /* defer-max */                                                           \
    if (!__all(mt_ <= m_s + THR)) {                                           \
      float mn_ = fmaxf(m_s, mt_);                                            \
      float al_ = exp2f((m_s - mn_) * LOG2E);                                 \
      m_s = mn_;                                                              \
      mLs = mn_ * LOG2E;                                                      \
      l_s *= al_;                                                             \
      float a0_ = __shfl(al_, (lane & 48) | hi4);                             \
      float a1_ = __shfl(al_, (lane & 48) | (hi4 + 1));                       \
      float a2_ = __shfl(al_, (lane & 48) | (hi4 + 2));                       \
      float a3_ = __shfl(al_, (lane & 48) | (hi4 + 3));                       \
      _Pragma("unroll") for (int f = 0; f < 4; ++f) {                         \
        o[f][0] *= a0_; o[f][1] *= a1_; o[f][2] *= a2_; o[f][3] *= a3_;       \
      }                                                                       \
    }                                                                         \
    /* P = exp2(sc*log2e - mLs), pack pairs (consecutive k) to bf16 */        \
    unsigned pk_[4][2];                                                       \
    _Pragma("unroll") for (int f = 0; f < 4; ++f) {                           \
      float p0_ = exp2f(fmaf(sf[f][0], LOG2E, -mLs));                         \
      float p1_ = exp2f(fmaf(sf[f][1], LOG2E, -mLs));                         \
      float p2_ = exp2f(fmaf(sf[f][2], LOG2E, -mLs));                         \
      float p3_ = exp2f(fmaf(sf[f][3], LOG2E, -mLs));                         \
      l_s += (p0_ + p1_) + (p2_ + p3_);                                       \
      pk_[f][0] = packbf(p0_, p1_);                                           \
      pk_[f][1] = packbf(p2_, p3_);                                           \
    }                                                                         \
    /* PV: A-frag = register concat; V read with kv-permutation pi where    */\
    /* slot(8hi+e) -> kv = 32ks + 16*(e>=4) + 4hi + (e&3)  (R5-proven)      */\
    __builtin_amdgcn_s_setprio(1);                                            \
    _Pragma("unroll") for (int ks = 0; ks < 2; ++ks) {                        \
      uint4v au_;                                                             \
      au_[0] = pk_[2 * ks][0];                                                \
      au_[1] = pk_[2 * ks][1];                                                \
      au_[2] = pk_[2 * ks + 1][0];                                            \
      au_[3] = pk_[2 * ks + 1][1];                                            \
      short8v pa = __builtin_bit_cast(short8v, au_);                          \
      _Pragma("unroll") for (int f = 0; f < 4; ++f) {                         \
        int vrow_ = f * 16 + lq;                                              \
        int blkA_ = 4 * ks + (hi >> 1);                                       \
        int eA_ = vrow_ * 64 + (((blkA_) ^ (vrow_ & 7)) << 3) +               \
                  ((hi & 1) << 2);                                            \
        int eB_ = vrow_ * 64 + (((blkA_ + 2) ^ (vrow_ & 7)) << 3) +           \
                  ((hi & 1) << 2);                                            \
        short4v vlo_ = *(const short4v*)&Vs[CUR_][eA_];                       \
        short4v vhi_ = *(const short4v*)&Vs[CUR_][eB_];                       \
        short8v vb_;                                                          \
        vb_[0] = vlo_[0]; vb_[1] = vlo_[1]; vb_[2] = vlo_[2];                 \
        vb_[3] = vlo_[3]; vb_[4] = vhi_[0]; vb_[5] = vhi_[1];                 \
        vb_[6] = vhi_[2]; vb_[7] = vhi_[3];                                   \
        o[f] = mfma16(pa, vb_, o[f]);                                         \
      }                                                                       \
    }                                                                         \
    __builtin_amdgcn_s_setprio(0);                                            \
    __syncthreads();                                                          \
  } while (0)

__global__ __launch_bounds__(256, 4)
void attn_kernel(const unsigned short* __restrict__ Qb,
                 const unsigned short* __restrict__ Kb,
                 const unsigned short* __restrict__ VbT,
                 const float* __restrict__ mask,
                 unsigned short* __restrict__ vals) {
  __shared__ __align__(16) unsigned short Ks[2][64 * 64];
  __shared__ __align__(16) unsigned short Vs[2][64 * 64];
  int tid = threadIdx.x;
  int lane = tid & 63;
  int wid = tid >> 6;
  int lq = lane & 15;
  int hi = lane >> 4;
  int hi4 = hi << 2;
  int h = blockIdx.x & 15;           // h innermost: mask tile L2 reuse
  int qt = (blockIdx.x >> 4) & 31;
  int b = blockIdx.x >> 9;
  int bh = b * 16 + h;
  size_t bh_off = (size_t)bh * 2048 * 64;
  int q0 = qt * 64 + wid * 16;

  const unsigned short* qptr =
      Qb + bh_off + (size_t)(q0 + lq) * 64 + (hi << 3);
  short8v qa0 = *(const short8v*)qptr;
  short8v qa1 = *(const short8v*)(qptr + 32);

  f32x4 o[4] = {};
  float m_s = -1e30f, l_s = 0.f, mLs = 0.f;

  const float* mrowq = mask + ((size_t)b * 2048 + q0 + lq) * 2048 + hi4;

  const float THR = 4.0f;

  f32x4 mkA[4], mkB[4];
#pragma unroll
  for (int f = 0; f < 4; ++f) mkA[f] = *(const f32x4*)(mrowq + f * 16);
  ATTN_STAGE(0, 0);
  __syncthreads();

  for (int t = 0; t < 16; ++t) {
    ATTN_TILE(2 * t, 0, mkA, mkB);
    ATTN_TILE(2 * t + 1, 1, mkB, mkA);
  }

  // deferred row-sum reduction across hi lanes, then broadcast per o-row
  l_s += __shfl_xor(l_s, 16);
  l_s += __shfl_xor(l_s, 32);
  float ri_ = 1.0f / l_s;
  float rv_[4];
#pragma unroll
  for (int r = 0; r < 4; ++r) rv_[r] = __shfl(ri_, (lane & 48) | (hi4 + r));

  // epilogue: scrambled reshape (b,h,s,d) -> (b, h*128 + s/16, (s%16)*64 + d)
#pragma unroll
  for (int f = 0; f < 4; ++f)
#pragma unroll
    for (int r = 0; r < 4; ++r) {
      int s = q0 + hi4 + r;
      int d = f * 16 + lq;
      int s2 = h * 128 + (s >> 4);
      int c2 = ((s & 15) << 6) + d;
      vals[((size_t)b * 2048 + s2) * 1024 + c2] = f2bf(o[f][r] * rv_[r]);
    }
}

// ---------------------------------------------------------------------------
// Output GEMM: vals[4096,1024]bf16 @ WoT[1024,1024]bf16 + bo -> out f32.
// BM=128 BN=64 -> grid 512 (2 blocks/CU) + LDS dbuf. 4 waves, 64m x 32n each.

#define OUT_STAGE(k0_, bi_)                                                   \
  do {                                                                        \
    _Pragma("unroll") for (int it_ = 0; it_ < 4; ++it_) {                     \
      int G_ = it_ * 256 + tid;                                               \
      int r_ = G_ >> 3, g_ = G_ & 7;                                          \
      int sg_ = g_ ^ (r_ & 7);                                                \
      gload_lds16(vals + (size_t)(m0 + r_) * 1024 + (k0_) + sg_ * 8,          \
                  &As[bi_][G_ * 8]);                                          \
    }                                                                         \
    _Pragma("unroll") for (int it_ = 0; it_ < 2; ++it_) {                     \
      int G_ = it_ * 256 + tid;                                               \
      int r_ = G_ >> 3, g_ = G_ & 7;                                          \
      int sg_ = g_ ^ (r_ & 7);                                                \
      gload_lds16(WoT + (size_t)(n0 + r_) * 1024 + (k0_) + sg_ * 8,           \
                  &Bs[bi_][G_ * 8]);                                          \
    }                                                                         \
  } while (0)

#define OUT_STEP(k0_, CUR_)                                                   \
  do {                                                                        \
    if ((k0_) + 64 < 1024) OUT_STAGE((k0_) + 64, (CUR_) ^ 1);                 \
    _Pragma("unroll") for (int ks = 0; ks < 2; ++ks) {                        \
      short8v a_[4], b_[2];                                                   \
      int kg = ks * 4 + hi;                                                   \
      _Pragma("unroll") for (int i = 0; i < 4; ++i) {                         \
        int ra = wm + i * 16 + lq;                                            \
        a_[i] = *(const short8v*)&As[CUR_][ra * 64 + ((kg ^ (ra & 7)) << 3)]; \
      }                                                                       \
      _Pragma("unroll") for (int j = 0; j < 2; ++j) {                         \
        int rb = wn + j * 16 + lq;                                            \
        b_[j] = *(const short8v*)&Bs[CUR_][rb * 64 + ((kg ^ (rb & 7)) << 3)]; \
      }                                                                       \
      _Pragma("unroll") for (int i = 0; i < 4; ++i)                           \
          _Pragma("unroll") for (int j = 0; j < 2; ++j)                       \
              acc[i][j] = mfma16(a_[i], b_[j], acc[i][j]);                    \
    }                                                                         \
    __syncthreads();                                                          \
  } while (0)

__global__ __launch_bounds__(256, 2)
void gemm_out_kernel(const unsigned short* __restrict__ vals,
                     const unsigned short* __restrict__ WoT,
                     const float* __restrict__ bo,
                     float* __restrict__ out) {
  __shared__ __align__(16) unsigned short As[2][128 * 64];
  __shared__ __align__(16) unsigned short Bs[2][64 * 64];
  int tid = threadIdx.x;
  int lane = tid & 63;
  int wid = tid >> 6;
  int lq = lane & 15;
  int hi = lane >> 4;
  int m0 = blockIdx.y * 128;
  int n0 = blockIdx.x * 64;
  int wm = (wid >> 1) * 64;
  int wn = (wid & 1) * 32;
  f32x4 acc[4][2] = {};

  OUT_STAGE(0, 0);
  __syncthreads();
#pragma unroll 1
  for (int kk = 0; kk < 8; ++kk) {
    OUT_STEP(kk * 128, 0);
    OUT_STEP(kk * 128 + 64, 1);
  }

#pragma unroll
  for (int i = 0; i < 4; ++i) {
#pragma unroll
    for (int j = 0; j < 2; ++j) {
      int n = n0 + wn + j * 16 + lq;
      float bv = bo[n];
#pragma unroll
      for (int rg = 0; rg < 4; ++rg) {
        int m = m0 + wm + i * 16 + (hi << 2) + rg;
        out[(size_t)m * 1024 + n] = acc[i][j][rg] + bv;
      }
    }
  }
}

// ---------------------------------------------------------------------------
extern "C" void kernel_launch(void* const* d_in, const int* in_sizes, int n_in,
                              void* d_out, int out_size, void* d_ws,
                              size_t ws_size, hipStream_t stream) {
  const float* x    = (const float*)d_in[0];
  const float* mask = (const float*)d_in[1];
  const float* Wqkv = (const float*)d_in[2];
  const float* bqkv = (const float*)d_in[3];
  const float* Wo   = (const float*)d_in[4];
  const float* bo   = (const float*)d_in[5];
  float* out = (float*)d_out;

  char* ws = (char*)d_ws;
  // layout (bytes): xbf 8M | WqkvT 6M | WoT 2M | Qb 8M | Kb 8M | VbT 8M
  // vals aliases xbf (x dead after gemm_qkv). Total 40 MB.
  unsigned short* xbf   = (unsigned short*)(ws);
  unsigned short* WqkvT = (unsigned short*)(ws + 8388608);
  unsigned short* WoT   = (unsigned short*)(ws + 14680064);
  unsigned short* Qb    = (unsigned short*)(ws + 16777216);
  unsigned short* Kb    = (unsigned short*)(ws + 25165824);
  unsigned short* VbT   = (unsigned short*)(ws + 33554432);
  unsigned short* vals  = xbf;  // reuse

  hipLaunchKernelGGL(prep_kernel, dim3(5120), dim3(256), 0, stream,
                     (const float4*)x, (uint2*)xbf, Wqkv, WqkvT, Wo, WoT);
  hipLaunchKernelGGL(gemm_qkv_kernel, dim3(24, 32), dim3(256), 0, stream,
                     xbf, WqkvT, bqkv, Qb, Kb, VbT);
  hipLaunchKernelGGL(attn_kernel, dim3(1024), dim3(256), 0, stream,
                     Qb, Kb, VbT, mask, vals);
  hipLaunchKernelGGL(gemm_out_kernel, dim3(16, 32), dim3(256), 0, stream,
                     vals, WoT, bo, out);
}